// Round 1
// baseline (431.377 us; speedup 1.0000x reference)
//
#include <hip/hip_runtime.h>

// y[m, p*32+q] = sum_{r,s} x[m, r*32+s] * W2[p,r] * W1[q,s] + bias[p*32+q]
//   == (W2 · X_m · W1^T)[p,q],  X_m = reshape(x[m], 32, 32)
//
// One wave per row m. Stage 1: T = X·W1^T (2x mfma_32x32x16_bf16),
// LDS round-trip to re-layout T (C/D -> B operand), Stage 2: Y = W2·T.
// W1/W2/bias fragments are loop-invariant, preloaded once per wave.

typedef short bf16x8 __attribute__((ext_vector_type(8)));   // 8 bf16 = 4 VGPRs
typedef float f32x16 __attribute__((ext_vector_type(16)));  // C/D acc

#define MFMA32(A, B, C) __builtin_amdgcn_mfma_f32_32x32x16_bf16((A), (B), (C), 0, 0, 0)

// fp32 -> bf16 with round-to-nearest-even (bit manipulation; NaN irrelevant here)
__device__ __forceinline__ short f2bf(float f) {
    unsigned u = __builtin_bit_cast(unsigned, f);
    u = (u + 0x7fffu + ((u >> 16) & 1u)) >> 16;
    return (short)u;
}

constexpr int M_TOTAL = 8 * 8192;   // 65536 rows of 1024
constexpr int BLOCKS  = 2048;
constexpr int TPB     = 256;        // 4 waves/block
constexpr int NWAVES  = BLOCKS * (TPB / 64);  // 8192 waves -> 8 rows/wave

__global__ __launch_bounds__(TPB) void kron_mlp_kernel(
    const float* __restrict__ x,    // (65536, 1024)
    const float* __restrict__ w1,   // (32, 32): W1[q][s]
    const float* __restrict__ w2,   // (32, 32): W2[p][r]
    const float* __restrict__ bias, // (1024,)
    float* __restrict__ out)        // (65536, 1024)
{
    // Per-wave T buffer: 32 cols (q) x 8 chunks x 4 floats, XOR-swizzled chunks.
    __shared__ float lds_t[4 * 32 * 8 * 4];  // 16 KiB

    const int tid  = threadIdx.x;
    const int wid  = tid >> 6;
    const int lane = tid & 63;
    const int q    = lane & 31;   // C/D col; B col; A row (m-index)
    const int h    = lane >> 5;   // half-wave: k-range selector
    const int qx   = q & 7;       // XOR swizzle key

    float* tl = lds_t + wid * (32 * 8 * 4);

    // ---- loop-invariant fragments ----
    // B-frag of W1^T: element[k=8h+j][n=q] = W1[q][8h+j]  (frag1: +16)
    bf16x8 w1b0, w1b1;
    {
        const float* p0 = w1 + q * 32 + 8 * h;
        #pragma unroll
        for (int j = 0; j < 8; ++j) { w1b0[j] = f2bf(p0[j]); w1b1[j] = f2bf(p0[16 + j]); }
    }
    // A-frag of W2: element[m=q(=p)][k=8h+j] = W2[q][8h+j]  (frag1: +16)
    bf16x8 w2a0, w2a1;
    {
        const float* p0 = w2 + q * 32 + 8 * h;
        #pragma unroll
        for (int j = 0; j < 8; ++j) { w2a0[j] = f2bf(p0[j]); w2a1[j] = f2bf(p0[16 + j]); }
    }
    // bias per acc reg: row(reg) = (reg&3) + 8*(reg>>2) + 4h, col = q
    float bia[16];
    #pragma unroll
    for (int g = 0; g < 4; ++g)
        #pragma unroll
        for (int i = 0; i < 4; ++i)
            bia[4 * g + i] = bias[(i + 8 * g + 4 * h) * 32 + q];

    const int gwave = blockIdx.x * (TPB / 64) + wid;

    for (int m = gwave; m < M_TOTAL; m += NWAVES) {
        const float* xr = x + (size_t)m * 1024;

        // A-frag of X: element[m=q(=r)][k=8h+j] = x[r*32 + 8h + j] (frag1: +16)
        const float4 xa = *(const float4*)(xr + q * 32 + 8 * h);
        const float4 xb = *(const float4*)(xr + q * 32 + 8 * h + 4);
        const float4 xc = *(const float4*)(xr + q * 32 + 8 * h + 16);
        const float4 xd = *(const float4*)(xr + q * 32 + 8 * h + 20);

        bf16x8 a0, a1;
        a0[0] = f2bf(xa.x); a0[1] = f2bf(xa.y); a0[2] = f2bf(xa.z); a0[3] = f2bf(xa.w);
        a0[4] = f2bf(xb.x); a0[5] = f2bf(xb.y); a0[6] = f2bf(xb.z); a0[7] = f2bf(xb.w);
        a1[0] = f2bf(xc.x); a1[1] = f2bf(xc.y); a1[2] = f2bf(xc.z); a1[3] = f2bf(xc.w);
        a1[4] = f2bf(xd.x); a1[5] = f2bf(xd.y); a1[6] = f2bf(xd.z); a1[7] = f2bf(xd.w);

        // Stage 1: T = X · W1^T   (K=32 split into two K=16 MFMAs)
        f32x16 t = {};
        t = MFMA32(a0, w1b0, t);
        t = MFMA32(a1, w1b1, t);

        // C/D -> LDS: acc regs 4g..4g+3 = T rows (8g+4h)..(8g+4h+3), col q.
        // chunk c = row/4 = 2g+h, phys chunk = c ^ (q&7) (conflict-optimal b128)
        #pragma unroll
        for (int g = 0; g < 4; ++g) {
            float4 v = { t[4 * g + 0], t[4 * g + 1], t[4 * g + 2], t[4 * g + 3] };
            *(float4*)(tl + (q * 8 + ((2 * g + h) ^ qx)) * 4) = v;
        }

        // LDS -> B-frag of T: element[k=r][n=q]; lane needs rows 8h..8h+7 (tb0)
        // and 16+8h..16+8h+7 (tb1) of col q -> chunks {2h,2h+1,4+2h,5+2h}
        const float4 r0 = *(const float4*)(tl + (q * 8 + ((2 * h + 0) ^ qx)) * 4);
        const float4 r1 = *(const float4*)(tl + (q * 8 + ((2 * h + 1) ^ qx)) * 4);
        const float4 r2 = *(const float4*)(tl + (q * 8 + ((4 + 2 * h) ^ qx)) * 4);
        const float4 r3 = *(const float4*)(tl + (q * 8 + ((5 + 2 * h) ^ qx)) * 4);

        bf16x8 tb0, tb1;
        tb0[0] = f2bf(r0.x); tb0[1] = f2bf(r0.y); tb0[2] = f2bf(r0.z); tb0[3] = f2bf(r0.w);
        tb0[4] = f2bf(r1.x); tb0[5] = f2bf(r1.y); tb0[6] = f2bf(r1.z); tb0[7] = f2bf(r1.w);
        tb1[0] = f2bf(r2.x); tb1[1] = f2bf(r2.y); tb1[2] = f2bf(r2.z); tb1[3] = f2bf(r2.w);
        tb1[4] = f2bf(r3.x); tb1[5] = f2bf(r3.y); tb1[6] = f2bf(r3.z); tb1[7] = f2bf(r3.w);

        // Stage 2: Y = W2 · T
        f32x16 y = {};
        y = MFMA32(w2a0, tb0, y);
        y = MFMA32(w2a1, tb1, y);

        // Epilogue: bias + store (lanes 0..31 cover q=0..31 -> coalesced rows)
        float* orow = out + (size_t)m * 1024;
        #pragma unroll
        for (int g = 0; g < 4; ++g)
            #pragma unroll
            for (int i = 0; i < 4; ++i) {
                const int row = i + 8 * g + 4 * h;
                orow[row * 32 + q] = y[4 * g + i] + bia[4 * g + i];
            }
    }
}

extern "C" void kernel_launch(void* const* d_in, const int* in_sizes, int n_in,
                              void* d_out, int out_size, void* d_ws, size_t ws_size,
                              hipStream_t stream) {
    const float* x    = (const float*)d_in[0];
    const float* w1   = (const float*)d_in[1];
    const float* w2   = (const float*)d_in[2];
    const float* bias = (const float*)d_in[3];
    float* out        = (float*)d_out;
    kron_mlp_kernel<<<dim3(BLOCKS), dim3(TPB), 0, stream>>>(x, w1, w2, bias, out);
}